// Round 12
// baseline (220.774 us; speedup 1.0000x reference)
//
#include <hip/hip_runtime.h>

// ---------------- problem constants ----------------
#define NTOK   32768
#define DIM    512            // bytes per fp8 row too
#define NCODE  4096
#define NELEM  (NTOK*DIM)     // 16777216
#define COMMIT 0.25
#define ESCALE 8192.0f        // 2^13: lifts emb (~2.4e-4) into e4m3 normal range
#define KSCL   262144.0f      // 2^18 key quantizer
#define KOFF   65536.0f       // 0.25 * 2^18 (covers |s| <= 0.25 hard bound)
// score = en - acc*2^-12; key = fmaf(en,KSCL,KOFF) - 64*acc (EINV*KSCL = 64,
// same ordering/monotonicity, one fewer VALU op; verified in v4/v5 runs)

// ---------------- ws layout (bytes) ----------------
#define OFF_E8      16777216ULL       // fp8 e*8192: 2097152
#define OFF_EN32    18874368ULL       // float[4096] = 16384
#define OFF_DONE    18890752ULL       // u32 ticket (old rowmin region, unused)
#define OFF_COUNTS  19021824ULL       // u32[4096] = 16384
#define OFF_SSE     19038208ULL       // double[256] = 2048

typedef int   v8i  __attribute__((ext_vector_type(8)));
typedef float v16f __attribute__((ext_vector_type(16)));

#define GLOBAL_AS __attribute__((address_space(1)))
#define LDS_AS    __attribute__((address_space(3)))

__device__ __forceinline__ void gld16(const void* g, void* l) {
    // async global->LDS, 16B/lane; LDS dest = wave-uniform base + lane*16
    __builtin_amdgcn_global_load_lds((const GLOBAL_AS unsigned int*)g,
                                     (LDS_AS unsigned int*)l, 16, 0, 0);
}

// ---------------- 1. emb prep: fp8 conversion + ||e||^2 + inits -------------
__global__ void prep_kernel(const float* __restrict__ e,
                            unsigned* __restrict__ e8,
                            unsigned* __restrict__ counts, double* __restrict__ sse,
                            float* __restrict__ en32, unsigned* __restrict__ done) {
    int i = blockIdx.x * blockDim.x + threadIdx.x;     // 131072 threads
    if (i < NCODE) counts[i] = 0u;
    if (i < 256)   sse[i] = 0.0;
    if (i == 0)    *done = 0u;
    const float4* src = (const float4*)e;
    uint4 o;
    double nrm = 0.0;
#pragma unroll
    for (int q = 0; q < 4; q++) {
        float4 v = src[i * 4 + q];
        nrm += (double)v.x*v.x + (double)v.y*v.y + (double)v.z*v.z + (double)v.w*v.w;
        int r = 0;
        r = __builtin_amdgcn_cvt_pk_fp8_f32(v.x * ESCALE, v.y * ESCALE, r, false);
        r = __builtin_amdgcn_cvt_pk_fp8_f32(v.z * ESCALE, v.w * ESCALE, r, true);
        (&o.x)[q] = (unsigned)r;
    }
    ((uint4*)e8)[i] = o;
    // 32 consecutive lanes cover one emb row (512 floats) -> shfl reduction
#pragma unroll
    for (int off = 16; off; off >>= 1) nrm += __shfl_xor(nrm, off);
    if ((i & 31) == 0) en32[i >> 5] = (float)nrm;
}

// ---------------- 2. score pass: z-convert + matmul + gather + finalize -----
// v10 (212.7us total, best) plus:
//   - folded key math: pre = fmaf(en,KSCL,KOFF); kq = fmaf(sum,-64,pre).
//   - last-block finalize fusion: done-ticket after the sse atomicAdd; block
//     with ticket==gridDim-1 computes losses+perplexity. counts/sse read via
//     device-scope atomic reads (atomicOr 0 / atomicAdd 0.0) so per-XCD L2
//     staleness cannot serve stale values. All other blocks' atomics are
//     complete before their tickets (compiler drains vmcnt at each barrier;
//     threadfence orders sse-add before ticket increment).
// LDS stays EXACTLY 80KB (2-block boundary): flag lives in rmin[64], finalize
// scratch reuses sB0.
__global__ __launch_bounds__(256, 2)
void score_pass(const unsigned char* __restrict__ e8,
                const float* __restrict__ en32,
                const float* __restrict__ zf32, const float* __restrict__ embf,
                float* __restrict__ out, double* __restrict__ sse,
                unsigned* __restrict__ counts, unsigned* __restrict__ done) {
    __shared__ __align__(16) unsigned char sB0[64 * 512];   // e-tile buffer A
    __shared__ __align__(16) unsigned char sB1[64 * 512];   // z fp8, then e buffer B
    __shared__ __align__(16) float sEn[NCODE];               // 16KB code norms
    const int tid = threadIdx.x;
    const int row0 = blockIdx.x * 64;    // token rows of this block
    const int wv = tid >> 6, ln = tid & 63;
    const int wm = wv & 1;               // row half  (32 rows)
    const int wn = wv >> 1;              // col half  (32 codes of the 64-code tile)
    const int c = ln & 31, h = ln >> 5;

    // ---- stage en32 -> sEn (async DMA, drained by the __syncthreads below)
#pragma unroll
    for (int s = 0; s < 4; s++) {
        int chunk = wv * 4 + s;
        gld16((const unsigned char*)en32 + chunk * 1024 + (unsigned)(ln * 16),
              (unsigned char*)sEn + chunk * 1024);
    }

    // per-lane e-tile source offsets (ct-invariant)
    unsigned eoff[8];
#pragma unroll
    for (int s = 0; s < 8; s++) {
        int q = wv * 8 + s;
        int r = 2 * q + h;               // row within 64-code tile
        unsigned g = (unsigned)((ln & 31) ^ (r & 31));
        eoff[s] = (unsigned)(r * 512) + g * 16u;
    }
    // ---- stage e-tile 0 into sB0 (async DMA)
#pragma unroll
    for (int s = 0; s < 8; s++)
        gld16(e8 + eoff[s], sB0 + (wv * 8 + s) * 1024);

    // ---- convert this block's 64 z rows fp32 -> fp8 into sB1 (swizzled)
    // granule gi = r*32+g covers row r floats [g*16,(g+1)*16) = zsrc[4*gi+q];
    // dest slot = g ^ (r&31). Consecutive tid -> consecutive g: coalesced.
    {
        const float4* zsrc = (const float4*)(zf32 + (size_t)row0 * 512);
#pragma unroll
        for (int s = 0; s < 8; s++) {
            int gi = tid + s * 256;      // 0..2047
            int r = gi >> 5, g = gi & 31;
            uint4 o;
#pragma unroll
            for (int q = 0; q < 4; q++) {
                float4 v = zsrc[4 * gi + q];
                int rr = 0;
                rr = __builtin_amdgcn_cvt_pk_fp8_f32(v.x, v.y, rr, false);
                rr = __builtin_amdgcn_cvt_pk_fp8_f32(v.z, v.w, rr, true);
                (&o.x)[q] = (unsigned)rr;
            }
            *(uint4*)(sB1 + r * 512 + ((g ^ (r & 31)) << 4)) = o;
        }
    }
    __syncthreads();                     // full drain: z conv + en + tile0 resident

    // ---- hoist this wave's A fragments (32 z rows x K=512) into registers
    const int mrow = (wm * 32 + c) * 512;
    const int nrow = (wn * 32 + c) * 512;
    v8i za[8];
#pragma unroll
    for (int kt = 0; kt < 8; kt++) {
        int G = kt * 4 + 2 * h;
        uint4 x0 = *(const uint4*)(sB1 + mrow + (((G    ) ^ c) * 16));
        uint4 x1 = *(const uint4*)(sB1 + mrow + (((G + 1) ^ c) * 16));
        za[kt] = (v8i){(int)x0.x, (int)x0.y, (int)x0.z, (int)x0.w,
                       (int)x1.x, (int)x1.y, (int)x1.z, (int)x1.w};
    }
    asm volatile("s_waitcnt lgkmcnt(0)" ::: "memory");
    __builtin_amdgcn_s_barrier();        // all waves done with sB1 -> free

    // ---- stage e-tile 1 into sB1
#pragma unroll
    for (int s = 0; s < 8; s++)
        gld16(e8 + 32768 + eoff[s], sB1 + (wv * 8 + s) * 1024);

    unsigned runmin[16];
#pragma unroll
    for (int reg = 0; reg < 16; reg++) runmin[reg] = 0xFFFFFFFFu;

    for (int ct = 0; ct < 64; ct++) {
        // tile ct resident check: the 8 newest in-flight ops are tile ct+1's
        if (ct == 63) asm volatile("s_waitcnt vmcnt(0)" ::: "memory");
        else          asm volatile("s_waitcnt vmcnt(8)" ::: "memory");
        __builtin_amdgcn_s_barrier();

        const unsigned char* sB = (ct & 1) ? sB1 : sB0;
        float en = sEn[ct * 64 + wn * 32 + c];    // this lane's code norm
        float pre = fmaf(en, KSCL, KOFF);
        v16f acc0 = (v16f)(0.0f), acc1 = (v16f)(0.0f);
#pragma unroll
        for (int kt = 0; kt < 8; kt++) {
            int G = kt * 4 + 2 * h;
            uint4 y0 = *(const uint4*)(sB + nrow + (((G    ) ^ c) * 16));
            uint4 y1 = *(const uint4*)(sB + nrow + (((G + 1) ^ c) * 16));
            v8i b = (v8i){(int)y0.x, (int)y0.y, (int)y0.z, (int)y0.w,
                          (int)y1.x, (int)y1.y, (int)y1.z, (int)y1.w};
            if (kt & 1)
                acc1 = __builtin_amdgcn_mfma_scale_f32_32x32x64_f8f6f4(
                    za[kt], b, acc1, 0, 0, 0, 0x7F, 0, 0x7F);
            else
                acc0 = __builtin_amdgcn_mfma_scale_f32_32x32x64_f8f6f4(
                    za[kt], b, acc0, 0, 0, 0, 0x7F, 0, 0x7F);
        }

        unsigned n = (unsigned)(ct * 64 + wn * 32 + c);
#pragma unroll
        for (int reg = 0; reg < 16; reg++) {
            float s0 = acc0[reg] + acc1[reg];
            unsigned kq = (unsigned)fmaf(s0, -64.0f, pre);   // trunc; monotone
            unsigned p = (kq << 12) | n;
            runmin[reg] = runmin[reg] < p ? runmin[reg] : p;
        }

        asm volatile("s_waitcnt lgkmcnt(0)" ::: "memory"); // ds reads of buf done
        __builtin_amdgcn_s_barrier();     // all waves done reading buf[ct&1]

        if (ct < 62) {                    // stage tile ct+2 into buf[ct&1]
            unsigned char* sD = (ct & 1) ? sB1 : sB0;
            const unsigned char* ebase = e8 + (size_t)(ct + 2) * 32768;
#pragma unroll
            for (int s = 0; s < 8; s++)
                gld16(ebase + eoff[s], sD + (wv * 8 + s) * 1024);
        }
    }

    // ---- cross-lane reduce (32 cols per half), then cross-wn combine via LDS
    __syncthreads();                      // done with buffers -> reuse as scratch
    unsigned* tmp = (unsigned*)sB0;       // [4 waves][32 rows]
#pragma unroll
    for (int reg = 0; reg < 16; reg++) {
        unsigned v = runmin[reg];
#pragma unroll
        for (int off = 1; off < 32; off <<= 1) {
            unsigned o = (unsigned)__shfl_xor((int)v, off);
            v = v < o ? v : o;
        }
        if (c == 0) {
            int rr = (reg & 3) + 8 * (reg >> 2) + 4 * h;   // row within 32-half
            tmp[(wm * 2 + wn) * 32 + rr] = v;
        }
    }
    __syncthreads();
    unsigned* rmin = (unsigned*)sB1;      // final per-row code, LDS-resident
    if (tid < 64) {                       // row br = tid: combine the two wn halves
        int wmb = tid >> 5, rr = tid & 31;
        unsigned v0 = tmp[(wmb * 2 + 0) * 32 + rr];
        unsigned v1 = tmp[(wmb * 2 + 1) * 32 + rr];
        unsigned best = v0 < v1 ? v0 : v1;
        rmin[tid] = best & 0xFFFu;
        atomicAdd(&counts[best & 0xFFFu], 1u);   // fused histogram
    }
    __syncthreads();

    // ---- fused gather + STE output + sse for this block's 64 rows ----------
    const float4* zf = (const float4*)(zf32 + (size_t)row0 * 512);
    float4*       of = (float4*)(out + (size_t)row0 * 512);
    const float4* ef = (const float4*)embf;
    double loc = 0.0;
#pragma unroll 4
    for (int it = 0; it < 32; it++) {
        int idx = tid + it * 256;
        int row = idx >> 7, col = idx & 127;
        unsigned code = rmin[row];
        float4 zv = zf[idx];
        float4 q  = ef[code * 128 + col];
        float dx = q.x - zv.x, dy = q.y - zv.y, dz = q.z - zv.z, dw = q.w - zv.w;
        of[idx] = make_float4(zv.x + dx, zv.y + dy, zv.z + dz, zv.w + dw);
        loc += (double)dx*dx + (double)dy*dy + (double)dz*dz + (double)dw*dw;
    }
    for (int off = 32; off; off >>= 1) loc += __shfl_down(loc, off);
    double* sw = (double*)sEn;            // sEn free -> double scratch
    if (ln == 0) sw[wv] = loc;
    __syncthreads();
    if (tid == 0) {
        atomicAdd(&sse[blockIdx.x & 255], sw[0] + sw[1] + sw[2] + sw[3]);
        __threadfence();                  // order sse-add before ticket
        unsigned t = atomicAdd(done, 1u);
        rmin[64] = (t == (unsigned)gridDim.x - 1u) ? 1u : 0u;  // LDS flag
    }
    __syncthreads();
    if (rmin[64] == 0u) return;

    // ---- LAST BLOCK: finalize (losses + perplexity) -------------------------
    // Atomic reads = device-coherent (bypass possibly-stale per-XCD L2).
    double hsum = 0.0;
    for (int b = tid; b < NCODE; b += 256) {
        unsigned cnt = atomicOr(&counts[b], 0u);
        double p = (double)cnt / (double)NTOK;
        hsum += p * log(p + 1e-10);
    }
    double vsum = atomicAdd(&sse[tid], 0.0);
    double* sh = (double*)sB0;            // reuse buffer A as scratch
    double* sv = sh + 256;
    sh[tid] = hsum; sv[tid] = vsum;
    __syncthreads();
    for (int off = 128; off > 0; off >>= 1) {
        if (tid < off) { sh[tid] += sh[tid + off]; sv[tid] += sv[tid + off]; }
        __syncthreads();
    }
    if (tid == 0) {
        out[NELEM]     = (float)((1.0 + COMMIT) * sv[0] / (double)NELEM);  // vq_loss
        out[NELEM + 1] = (float)exp(-sh[0]);                                // perplexity
    }
}

// ---------------- launch ----------------
extern "C" void kernel_launch(void* const* d_in, const int* in_sizes, int n_in,
                              void* d_out, int out_size, void* d_ws, size_t ws_size,
                              hipStream_t stream) {
    const float* z   = (const float*)d_in[0];
    const float* emb = (const float*)d_in[1];
    float* out = (float*)d_out;
    char* ws = (char*)d_ws;

    unsigned* e8 = (unsigned*)(ws + OFF_E8);
    float*    en32 = (float*)(ws + OFF_EN32);
    unsigned* done = (unsigned*)(ws + OFF_DONE);
    unsigned* counts = (unsigned*)(ws + OFF_COUNTS);
    double*   sse    = (double*)(ws + OFF_SSE);

    prep_kernel<<<(NCODE * DIM / 16) / 256, 256, 0, stream>>>(
        emb, e8, counts, sse, en32, done);

    score_pass<<<NTOK / 64, 256, 0, stream>>>((const unsigned char*)e8, en32,
                                              z, emb, out, sse, counts, done);
}

// Round 13
// 205.486 us; speedup vs baseline: 1.0744x; 1.0744x over previous
//
#include <hip/hip_runtime.h>

// ---------------- problem constants ----------------
#define NTOK   32768
#define DIM    512            // bytes per fp8 row too
#define NCODE  4096
#define NELEM  (NTOK*DIM)     // 16777216
#define COMMIT 0.25
#define ESCALE 8192.0f        // 2^13: lifts emb (~2.4e-4) into e4m3 normal range
#define KSCL   262144.0f      // 2^18 key quantizer
#define KOFF   65536.0f       // 0.25 * 2^18 (covers |s| <= 0.25 hard bound)
// score = en - acc*2^-12; key = fmaf(acc,-64,fmaf(en,KSCL,KOFF)) (EINV*KSCL=64;
// verified numerically identical argmin in v4/v5 runs — same absmax)

// ---------------- ws layout (bytes) ----------------
#define OFF_E8      16777216ULL       // fp8 e*8192: 2097152
#define OFF_EN32    18874368ULL       // float[4096] = 16384
#define OFF_COUNTS  19021824ULL       // u32[4096] = 16384
#define OFF_SSE     19038208ULL       // double[256] = 2048

typedef int   v8i  __attribute__((ext_vector_type(8)));
typedef float v16f __attribute__((ext_vector_type(16)));

#define GLOBAL_AS __attribute__((address_space(1)))
#define LDS_AS    __attribute__((address_space(3)))

__device__ __forceinline__ void gld16(const void* g, void* l) {
    // async global->LDS, 16B/lane; LDS dest = wave-uniform base + lane*16
    __builtin_amdgcn_global_load_lds((const GLOBAL_AS unsigned int*)g,
                                     (LDS_AS unsigned int*)l, 16, 0, 0);
}

// ---------------- 1. emb prep: fp8 conversion + ||e||^2 + inits -------------
__global__ void prep_kernel(const float* __restrict__ e,
                            unsigned* __restrict__ e8,
                            unsigned* __restrict__ counts, double* __restrict__ sse,
                            float* __restrict__ en32) {
    int i = blockIdx.x * blockDim.x + threadIdx.x;     // 131072 threads
    if (i < NCODE) counts[i] = 0u;
    if (i < 256)   sse[i] = 0.0;
    const float4* src = (const float4*)e;
    uint4 o;
    double nrm = 0.0;
#pragma unroll
    for (int q = 0; q < 4; q++) {
        float4 v = src[i * 4 + q];
        nrm += (double)v.x*v.x + (double)v.y*v.y + (double)v.z*v.z + (double)v.w*v.w;
        int r = 0;
        r = __builtin_amdgcn_cvt_pk_fp8_f32(v.x * ESCALE, v.y * ESCALE, r, false);
        r = __builtin_amdgcn_cvt_pk_fp8_f32(v.z * ESCALE, v.w * ESCALE, r, true);
        (&o.x)[q] = (unsigned)r;
    }
    ((uint4*)e8)[i] = o;
    // 32 consecutive lanes cover one emb row (512 floats) -> shfl reduction
#pragma unroll
    for (int off = 16; off; off >>= 1) nrm += __shfl_xor(nrm, off);
    if ((i & 31) == 0) en32[i >> 5] = (float)nrm;
}

// ---------------- 2. score pass: fused z-convert + matmul + gather ----------
// v10 (212.7us total, best measured) with ONE change: folded key math
// (pre = fmaf(en,KSCL,KOFF) hoisted; kq = fmaf(sum,-64,pre)) — 2 fewer VALU
// ops per output in the deferred-score window that overlaps staging DMA.
// v11's last-block finalize fusion REVERTED: its single-block tail (~10us of
// L2-bypass atomic reads + f64 logs on 1 CU) + per-block threadfence cost
// more than the ~8us finalize dispatch it saved (m-r11 counters: score 142,
// MfmaUtil diluted to 19).
__global__ __launch_bounds__(256, 2)
void score_pass(const unsigned char* __restrict__ e8,
                const float* __restrict__ en32,
                const float* __restrict__ zf32, const float* __restrict__ embf,
                float* __restrict__ out, double* __restrict__ sse,
                unsigned* __restrict__ counts) {
    __shared__ __align__(16) unsigned char sB0[64 * 512];   // e-tile buffer A
    __shared__ __align__(16) unsigned char sB1[64 * 512];   // z fp8, then e buffer B
    __shared__ __align__(16) float sEn[NCODE];               // 16KB code norms
    const int tid = threadIdx.x;
    const int row0 = blockIdx.x * 64;    // token rows of this block
    const int wv = tid >> 6, ln = tid & 63;
    const int wm = wv & 1;               // row half  (32 rows)
    const int wn = wv >> 1;              // col half  (32 codes of the 64-code tile)
    const int c = ln & 31, h = ln >> 5;

    // ---- stage en32 -> sEn (async DMA, drained by the __syncthreads below)
#pragma unroll
    for (int s = 0; s < 4; s++) {
        int chunk = wv * 4 + s;
        gld16((const unsigned char*)en32 + chunk * 1024 + (unsigned)(ln * 16),
              (unsigned char*)sEn + chunk * 1024);
    }

    // per-lane e-tile source offsets (ct-invariant)
    unsigned eoff[8];
#pragma unroll
    for (int s = 0; s < 8; s++) {
        int q = wv * 8 + s;
        int r = 2 * q + h;               // row within 64-code tile
        unsigned g = (unsigned)((ln & 31) ^ (r & 31));
        eoff[s] = (unsigned)(r * 512) + g * 16u;
    }
    // ---- stage e-tile 0 into sB0 (async DMA)
#pragma unroll
    for (int s = 0; s < 8; s++)
        gld16(e8 + eoff[s], sB0 + (wv * 8 + s) * 1024);

    // ---- convert this block's 64 z rows fp32 -> fp8 into sB1 (swizzled)
    // granule gi = r*32+g covers row r floats [g*16,(g+1)*16) = zsrc[4*gi+q];
    // dest slot = g ^ (r&31). Consecutive tid -> consecutive g: coalesced.
    {
        const float4* zsrc = (const float4*)(zf32 + (size_t)row0 * 512);
#pragma unroll
        for (int s = 0; s < 8; s++) {
            int gi = tid + s * 256;      // 0..2047
            int r = gi >> 5, g = gi & 31;
            uint4 o;
#pragma unroll
            for (int q = 0; q < 4; q++) {
                float4 v = zsrc[4 * gi + q];
                int rr = 0;
                rr = __builtin_amdgcn_cvt_pk_fp8_f32(v.x, v.y, rr, false);
                rr = __builtin_amdgcn_cvt_pk_fp8_f32(v.z, v.w, rr, true);
                (&o.x)[q] = (unsigned)rr;
            }
            *(uint4*)(sB1 + r * 512 + ((g ^ (r & 31)) << 4)) = o;
        }
    }
    __syncthreads();                     // full drain: z conv + en + tile0 resident

    // ---- hoist this wave's A fragments (32 z rows x K=512) into registers
    const int mrow = (wm * 32 + c) * 512;
    const int nrow = (wn * 32 + c) * 512;
    v8i za[8];
#pragma unroll
    for (int kt = 0; kt < 8; kt++) {
        int G = kt * 4 + 2 * h;
        uint4 x0 = *(const uint4*)(sB1 + mrow + (((G    ) ^ c) * 16));
        uint4 x1 = *(const uint4*)(sB1 + mrow + (((G + 1) ^ c) * 16));
        za[kt] = (v8i){(int)x0.x, (int)x0.y, (int)x0.z, (int)x0.w,
                       (int)x1.x, (int)x1.y, (int)x1.z, (int)x1.w};
    }
    asm volatile("s_waitcnt lgkmcnt(0)" ::: "memory");
    __builtin_amdgcn_s_barrier();        // all waves done with sB1 -> free

    // ---- stage e-tile 1 into sB1
#pragma unroll
    for (int s = 0; s < 8; s++)
        gld16(e8 + 32768 + eoff[s], sB1 + (wv * 8 + s) * 1024);

    unsigned runmin[16];
#pragma unroll
    for (int reg = 0; reg < 16; reg++) runmin[reg] = 0xFFFFFFFFu;

    for (int ct = 0; ct < 64; ct++) {
        // tile ct resident check: the 8 newest in-flight ops are tile ct+1's
        if (ct == 63) asm volatile("s_waitcnt vmcnt(0)" ::: "memory");
        else          asm volatile("s_waitcnt vmcnt(8)" ::: "memory");
        __builtin_amdgcn_s_barrier();

        const unsigned char* sB = (ct & 1) ? sB1 : sB0;
        float en = sEn[ct * 64 + wn * 32 + c];    // this lane's code norm
        float pre = fmaf(en, KSCL, KOFF);
        v16f acc0 = (v16f)(0.0f), acc1 = (v16f)(0.0f);
#pragma unroll
        for (int kt = 0; kt < 8; kt++) {
            int G = kt * 4 + 2 * h;
            uint4 y0 = *(const uint4*)(sB + nrow + (((G    ) ^ c) * 16));
            uint4 y1 = *(const uint4*)(sB + nrow + (((G + 1) ^ c) * 16));
            v8i b = (v8i){(int)y0.x, (int)y0.y, (int)y0.z, (int)y0.w,
                          (int)y1.x, (int)y1.y, (int)y1.z, (int)y1.w};
            if (kt & 1)
                acc1 = __builtin_amdgcn_mfma_scale_f32_32x32x64_f8f6f4(
                    za[kt], b, acc1, 0, 0, 0, 0x7F, 0, 0x7F);
            else
                acc0 = __builtin_amdgcn_mfma_scale_f32_32x32x64_f8f6f4(
                    za[kt], b, acc0, 0, 0, 0, 0x7F, 0, 0x7F);
        }

        unsigned n = (unsigned)(ct * 64 + wn * 32 + c);
#pragma unroll
        for (int reg = 0; reg < 16; reg++) {
            float s0 = acc0[reg] + acc1[reg];
            unsigned kq = (unsigned)fmaf(s0, -64.0f, pre);   // trunc; monotone
            unsigned p = (kq << 12) | n;
            runmin[reg] = runmin[reg] < p ? runmin[reg] : p;
        }

        asm volatile("s_waitcnt lgkmcnt(0)" ::: "memory"); // ds reads of buf done
        __builtin_amdgcn_s_barrier();     // all waves done reading buf[ct&1]

        if (ct < 62) {                    // stage tile ct+2 into buf[ct&1]
            unsigned char* sD = (ct & 1) ? sB1 : sB0;
            const unsigned char* ebase = e8 + (size_t)(ct + 2) * 32768;
#pragma unroll
            for (int s = 0; s < 8; s++)
                gld16(ebase + eoff[s], sD + (wv * 8 + s) * 1024);
        }
    }

    // ---- cross-lane reduce (32 cols per half), then cross-wn combine via LDS
    __syncthreads();                      // done with buffers -> reuse as scratch
    unsigned* tmp = (unsigned*)sB0;       // [4 waves][32 rows]
#pragma unroll
    for (int reg = 0; reg < 16; reg++) {
        unsigned v = runmin[reg];
#pragma unroll
        for (int off = 1; off < 32; off <<= 1) {
            unsigned o = (unsigned)__shfl_xor((int)v, off);
            v = v < o ? v : o;
        }
        if (c == 0) {
            int rr = (reg & 3) + 8 * (reg >> 2) + 4 * h;   // row within 32-half
            tmp[(wm * 2 + wn) * 32 + rr] = v;
        }
    }
    __syncthreads();
    unsigned* rmin = (unsigned*)sB1;      // final per-row code, LDS-resident
    if (tid < 64) {                       // row br = tid: combine the two wn halves
        int wmb = tid >> 5, rr = tid & 31;
        unsigned v0 = tmp[(wmb * 2 + 0) * 32 + rr];
        unsigned v1 = tmp[(wmb * 2 + 1) * 32 + rr];
        unsigned best = v0 < v1 ? v0 : v1;
        rmin[tid] = best & 0xFFFu;
        atomicAdd(&counts[best & 0xFFFu], 1u);   // fused histogram
    }
    __syncthreads();

    // ---- fused gather + STE output + sse for this block's 64 rows ----------
    const float4* zf = (const float4*)(zf32 + (size_t)row0 * 512);
    float4*       of = (float4*)(out + (size_t)row0 * 512);
    const float4* ef = (const float4*)embf;
    double loc = 0.0;
#pragma unroll 4
    for (int it = 0; it < 32; it++) {
        int idx = tid + it * 256;
        int row = idx >> 7, col = idx & 127;
        unsigned code = rmin[row];
        float4 zv = zf[idx];
        float4 q  = ef[code * 128 + col];
        float dx = q.x - zv.x, dy = q.y - zv.y, dz = q.z - zv.z, dw = q.w - zv.w;
        of[idx] = make_float4(zv.x + dx, zv.y + dy, zv.z + dz, zv.w + dw);
        loc += (double)dx*dx + (double)dy*dy + (double)dz*dz + (double)dw*dw;
    }
    for (int off = 32; off; off >>= 1) loc += __shfl_down(loc, off);
    double* sw = (double*)sEn;            // sEn free -> double scratch
    if (ln == 0) sw[wv] = loc;
    __syncthreads();
    if (tid == 0)
        atomicAdd(&sse[blockIdx.x & 255], sw[0] + sw[1] + sw[2] + sw[3]);
}

// ---------------- 3. losses + perplexity -------------
__global__ void finalize(const unsigned* __restrict__ counts, const double* __restrict__ sse,
                         float* __restrict__ out) {
    __shared__ double sh[256], sv[256];
    double h = 0.0;
    for (int b = threadIdx.x; b < NCODE; b += 256) {
        double p = (double)counts[b] / (double)NTOK;
        h += p * log(p + 1e-10);
    }
    sh[threadIdx.x] = h;
    sv[threadIdx.x] = sse[threadIdx.x];
    __syncthreads();
    for (int off = 128; off > 0; off >>= 1) {
        if (threadIdx.x < off) {
            sh[threadIdx.x] += sh[threadIdx.x + off];
            sv[threadIdx.x] += sv[threadIdx.x + off];
        }
        __syncthreads();
    }
    if (threadIdx.x == 0) {
        out[NELEM]     = (float)((1.0 + COMMIT) * sv[0] / (double)NELEM);  // vq_loss
        out[NELEM + 1] = (float)exp(-sh[0]);                                // perplexity
    }
}

// ---------------- launch ----------------
extern "C" void kernel_launch(void* const* d_in, const int* in_sizes, int n_in,
                              void* d_out, int out_size, void* d_ws, size_t ws_size,
                              hipStream_t stream) {
    const float* z   = (const float*)d_in[0];
    const float* emb = (const float*)d_in[1];
    float* out = (float*)d_out;
    char* ws = (char*)d_ws;

    unsigned* e8 = (unsigned*)(ws + OFF_E8);
    float*    en32 = (float*)(ws + OFF_EN32);
    unsigned* counts = (unsigned*)(ws + OFF_COUNTS);
    double*   sse    = (double*)(ws + OFF_SSE);

    prep_kernel<<<(NCODE * DIM / 16) / 256, 256, 0, stream>>>(
        emb, e8, counts, sse, en32);

    score_pass<<<NTOK / 64, 256, 0, stream>>>((const unsigned char*)e8, en32,
                                              z, emb, out, sse, counts);

    finalize<<<1, 256, 0, stream>>>(counts, sse, out);
}